// Round 5
// baseline (280.814 us; speedup 1.0000x reference)
//
#include <hip/hip_runtime.h>
#include <cstddef>

typedef short s4v __attribute__((ext_vector_type(4)));
typedef short s8v __attribute__((ext_vector_type(8)));
typedef float f4v __attribute__((ext_vector_type(4)));

__device__ __forceinline__ unsigned short f2bf(float f) {
    union { float f; unsigned u; } v; v.f = f;
    unsigned r = v.u + 0x7fff + ((v.u >> 16) & 1);
    return (unsigned short)(r >> 16);
}
__device__ __forceinline__ float bf2f(unsigned short u) {
    union { unsigned u; float f; } v; v.u = ((unsigned)u) << 16;
    return v.f;
}

// async global->LDS, 16B per lane. LDS dest is wave-uniform base + lane*16.
__device__ __forceinline__ void gl_lds16(const void* g, void* l) {
    __builtin_amdgcn_global_load_lds(
        (const __attribute__((address_space(1))) void*)g,
        (__attribute__((address_space(3))) void*)l, 16, 0, 0);
}

#define QSC   0.18033688011112043f   /* 0.125 * log2(e) */
#define EOFF  23.082320654223414f    /* 16 * log2(e) */

// ---------------------------------------------------------------------------
// Fused f32 -> bf16 conversion for x, qkv_w, proj_w (one launch).
// ---------------------------------------------------------------------------
__global__ __launch_bounds__(256) void to_bf16_all(
    const float* __restrict__ x, const float* __restrict__ qw,
    const float* __restrict__ pw, unsigned short* __restrict__ xd,
    unsigned short* __restrict__ qd, unsigned short* __restrict__ pd)
{
    int i = blockIdx.x * 256 + threadIdx.x;
    const float* s; unsigned short* d; int j;
    if (i < 786432)       { s = x;  d = xd; j = i; }
    else if (i < 1007616) { s = qw; d = qd; j = i - 786432; }
    else                  { s = pw; d = pd; j = i - 1007616; }
    float4 f0 = ((const float4*)s)[j * 2];
    float4 f1 = ((const float4*)s)[j * 2 + 1];
    uint4 pk;
    pk.x = (unsigned)f2bf(f0.x) | ((unsigned)f2bf(f0.y) << 16);
    pk.y = (unsigned)f2bf(f0.z) | ((unsigned)f2bf(f0.w) << 16);
    pk.z = (unsigned)f2bf(f1.x) | ((unsigned)f2bf(f1.y) << 16);
    pk.w = (unsigned)f2bf(f1.z) | ((unsigned)f2bf(f1.w) << 16);
    ((uint4*)d)[j] = pk;
}

// ---------------------------------------------------------------------------
// bf16 MFMA GEMM, m97 structure: 128x128 tile, BK=32, 256 thr = 4 waves.
// ---------------------------------------------------------------------------
__global__ __launch_bounds__(256) void qkv_gemm_mfma(
    const unsigned short* __restrict__ A, const unsigned short* __restrict__ W,
    const float* __restrict__ bias,
    unsigned short* __restrict__ qb, unsigned short* __restrict__ kb,
    unsigned short* __restrict__ vt)
{
    __shared__ __align__(16) unsigned short As[128 * 32];
    __shared__ __align__(16) unsigned short Bs[128 * 32];
    const int t     = threadIdx.x;
    const int bc    = blockIdx.x;   // N = 2304 -> 18
    const int br    = blockIdx.y;   // M = 8192 -> 64
    const int wv    = t >> 6;
    const int lane  = t & 63;
    const int col16 = lane & 15;
    const int quad  = lane >> 4;
    const int w4    = lane >> 2;
    const int k8    = (lane & 3) << 3;
    const int mw    = wv >> 1, nw = wv & 1;

    const unsigned short* Ag = A + (size_t)(br * 128 + (wv << 5) + w4) * 768 + k8;
    const unsigned short* Wg = W + (size_t)(bc * 128 + (wv << 5) + w4) * 768 + k8;
    unsigned short* Asw = &As[(wv << 5) * 32];
    unsigned short* Bsw = &Bs[(wv << 5) * 32];

    f4v acc[4][4];
#pragma unroll
    for (int mt = 0; mt < 4; ++mt)
#pragma unroll
        for (int nt = 0; nt < 4; ++nt) {
            acc[mt][nt][0] = 0.f; acc[mt][nt][1] = 0.f;
            acc[mt][nt][2] = 0.f; acc[mt][nt][3] = 0.f;
        }

    for (int k0 = 0; k0 < 768; k0 += 32) {
        __syncthreads();
        gl_lds16(Ag + k0,             Asw);
        gl_lds16(Ag + k0 + 16 * 768,  Asw + 16 * 32);
        gl_lds16(Wg + k0,             Bsw);
        gl_lds16(Wg + k0 + 16 * 768,  Bsw + 16 * 32);
        __syncthreads();

        s8v a[4], b[4];
#pragma unroll
        for (int mt = 0; mt < 4; ++mt)
            a[mt] = *(const s8v*)&As[(mw * 64 + mt * 16 + col16) * 32 + quad * 8];
#pragma unroll
        for (int nt = 0; nt < 4; ++nt)
            b[nt] = *(const s8v*)&Bs[(nw * 64 + nt * 16 + col16) * 32 + quad * 8];
#pragma unroll
        for (int mt = 0; mt < 4; ++mt)
#pragma unroll
            for (int nt = 0; nt < 4; ++nt)
                acc[mt][nt] = __builtin_amdgcn_mfma_f32_16x16x32_bf16(
                    a[mt], b[nt], acc[mt][nt], 0, 0, 0);
    }

    const int which = bc / 6;
    const int cb    = (bc % 6) * 128 + nw * 64;
    const int m0    = br * 128 + mw * 64 + quad * 4;
    if (which == 2) {
        // V transposed: [bh][d][tok], 4 consecutive toks per b64 store
#pragma unroll
        for (int nt = 0; nt < 4; ++nt) {
            int c    = cb + nt * 16 + col16;
            int head = c >> 6, d = c & 63;
            float bv = bias[1536 + c];
#pragma unroll
            for (int mt = 0; mt < 4; ++mt) {
                int mb  = m0 + mt * 16;
                int bbk = mb >> 10, tok = mb & 1023;
                uint2 pk;
                pk.x = (unsigned)f2bf(acc[mt][nt][0] + bv)
                     | ((unsigned)f2bf(acc[mt][nt][1] + bv) << 16);
                pk.y = (unsigned)f2bf(acc[mt][nt][2] + bv)
                     | ((unsigned)f2bf(acc[mt][nt][3] + bv) << 16);
                *(uint2*)&vt[((size_t)(bbk * 12 + head)) * 65536 + (size_t)d * 1024 + tok] = pk;
            }
        }
    } else {
        // q carries 0.125*log2e so downstream softmax can use exp2 directly
        const float sc = (which == 0) ? QSC : 1.0f;
        unsigned short* dst = (which == 0) ? qb : kb;
#pragma unroll
        for (int nt = 0; nt < 4; ++nt) {
            int c    = cb + nt * 16 + col16;
            int head = c >> 6, d = c & 63;
            float bv = bias[which * 768 + c];
#pragma unroll
            for (int mt = 0; mt < 4; ++mt) {
#pragma unroll
                for (int i = 0; i < 4; ++i) {
                    int m   = m0 + mt * 16 + i;
                    int bbk = m >> 10, tok = m & 1023;
                    dst[(((size_t)(bbk * 12 + head) << 10) + tok) * 64 + d] =
                        f2bf((acc[mt][nt][i] + bv) * sc);
                }
            }
        }
    }
}

__global__ __launch_bounds__(256) void proj_gemm_mfma(
    const unsigned short* __restrict__ A, const unsigned short* __restrict__ W,
    const float* __restrict__ bias, float* __restrict__ Out)
{
    __shared__ __align__(16) unsigned short As[128 * 32];
    __shared__ __align__(16) unsigned short Bs[128 * 32];
    const int t     = threadIdx.x;
    const int bc    = blockIdx.x;
    const int br    = blockIdx.y;
    const int wv    = t >> 6;
    const int lane  = t & 63;
    const int col16 = lane & 15;
    const int quad  = lane >> 4;
    const int w4    = lane >> 2;
    const int k8    = (lane & 3) << 3;
    const int mw    = wv >> 1, nw = wv & 1;

    const unsigned short* Ag = A + (size_t)(br * 128 + (wv << 5) + w4) * 768 + k8;
    const unsigned short* Wg = W + (size_t)(bc * 128 + (wv << 5) + w4) * 768 + k8;
    unsigned short* Asw = &As[(wv << 5) * 32];
    unsigned short* Bsw = &Bs[(wv << 5) * 32];

    f4v acc[4][4];
#pragma unroll
    for (int mt = 0; mt < 4; ++mt)
#pragma unroll
        for (int nt = 0; nt < 4; ++nt) {
            acc[mt][nt][0] = 0.f; acc[mt][nt][1] = 0.f;
            acc[mt][nt][2] = 0.f; acc[mt][nt][3] = 0.f;
        }

    for (int k0 = 0; k0 < 768; k0 += 32) {
        __syncthreads();
        gl_lds16(Ag + k0,             Asw);
        gl_lds16(Ag + k0 + 16 * 768,  Asw + 16 * 32);
        gl_lds16(Wg + k0,             Bsw);
        gl_lds16(Wg + k0 + 16 * 768,  Bsw + 16 * 32);
        __syncthreads();

        s8v a[4], b[4];
#pragma unroll
        for (int mt = 0; mt < 4; ++mt)
            a[mt] = *(const s8v*)&As[(mw * 64 + mt * 16 + col16) * 32 + quad * 8];
#pragma unroll
        for (int nt = 0; nt < 4; ++nt)
            b[nt] = *(const s8v*)&Bs[(nw * 64 + nt * 16 + col16) * 32 + quad * 8];
#pragma unroll
        for (int mt = 0; mt < 4; ++mt)
#pragma unroll
            for (int nt = 0; nt < 4; ++nt)
                acc[mt][nt] = __builtin_amdgcn_mfma_f32_16x16x32_bf16(
                    a[mt], b[nt], acc[mt][nt], 0, 0, 0);
    }

    const int m0 = br * 128 + mw * 64 + quad * 4;
#pragma unroll
    for (int nt = 0; nt < 4; ++nt) {
        int c    = bc * 128 + nw * 64 + nt * 16 + col16;
        float bv = bias[c];
#pragma unroll
        for (int mt = 0; mt < 4; ++mt) {
#pragma unroll
            for (int i = 0; i < 4; ++i) {
                int m = m0 + mt * 16 + i;
                Out[(size_t)m * 768 + c] = acc[mt][nt][i] + bv;
            }
        }
    }
}

// ---------------------------------------------------------------------------
// Bias-table precompute via MFMA.
// ---------------------------------------------------------------------------
__global__ __launch_bounds__(256) void bias_prep_mfma(
    const unsigned short* __restrict__ Q, const float* __restrict__ Rh,
    const float* __restrict__ Rw, unsigned short* __restrict__ qhb,
    unsigned short* __restrict__ qwb)
{
    __shared__ __align__(16) char smem[36864];
    unsigned short (*Qs)[72]  = (unsigned short (*)[72])smem;
    unsigned short (*Rs)[72]  = (unsigned short (*)[72])(smem + 18432);
    unsigned short (*Wsm)[72] = (unsigned short (*)[72])(smem + 27648);
    float (*G)[66]            = (float (*)[66])smem;

    const int t    = threadIdx.x;
    const int tc8  = blockIdx.x;   // 0..7 : 128-token chunk
    const int bh   = blockIdx.y;   // 0..95
    const int tok0 = tc8 << 7;

    for (int id = t; id < 1024; id += 256) {
        int row = id >> 3, g8 = (id & 7) << 3;
        *(uint4*)&Qs[row][g8] =
            *(const uint4*)(Q + ((size_t)bh * 1024 + tok0 + row) * 64 + g8);
    }
    for (int id = t; id < 512; id += 256) {
        int row = id >> 3, g8 = (id & 7) << 3;
        unsigned short* dh = &Rs[row][g8];
        unsigned short* dw = &Wsm[row][g8];
        if (row < 63) {
            const float* sh = Rh + row * 64 + g8;
            const float* sw = Rw + row * 64 + g8;
            float4 a = *(const float4*)sh; float4 b = *(const float4*)(sh + 4);
            float4 c = *(const float4*)sw; float4 d = *(const float4*)(sw + 4);
            dh[0] = f2bf(a.x); dh[1] = f2bf(a.y); dh[2] = f2bf(a.z); dh[3] = f2bf(a.w);
            dh[4] = f2bf(b.x); dh[5] = f2bf(b.y); dh[6] = f2bf(b.z); dh[7] = f2bf(b.w);
            dw[0] = f2bf(c.x); dw[1] = f2bf(c.y); dw[2] = f2bf(c.z); dw[3] = f2bf(c.w);
            dw[4] = f2bf(d.x); dw[5] = f2bf(d.y); dw[6] = f2bf(d.z); dw[7] = f2bf(d.w);
        } else {
#pragma unroll
            for (int j = 0; j < 8; ++j) { dh[j] = 0; dw[j] = 0; }
        }
    }
    __syncthreads();

    const int wv    = t >> 6;
    const int lane  = t & 63;
    const int col16 = lane & 15;
    const int quad  = lane >> 4;
    const int r0    = wv << 5;

    s8v qa[2][2], rb[4][2], wb[4][2];
#pragma unroll
    for (int mt = 0; mt < 2; ++mt)
#pragma unroll
        for (int kc = 0; kc < 2; ++kc)
            qa[mt][kc] = *(const s8v*)&Qs[r0 + mt * 16 + col16][kc * 32 + quad * 8];
#pragma unroll
    for (int nt = 0; nt < 4; ++nt)
#pragma unroll
        for (int kc = 0; kc < 2; ++kc) {
            rb[nt][kc] = *(const s8v*)&Rs[nt * 16 + col16][kc * 32 + quad * 8];
            wb[nt][kc] = *(const s8v*)&Wsm[nt * 16 + col16][kc * 32 + quad * 8];
        }

    f4v ah[2][4], aw[2][4];
#pragma unroll
    for (int mt = 0; mt < 2; ++mt)
#pragma unroll
        for (int nt = 0; nt < 4; ++nt) {
            f4v z; z[0] = 0.f; z[1] = 0.f; z[2] = 0.f; z[3] = 0.f;
            ah[mt][nt] = z; aw[mt][nt] = z;
        }
#pragma unroll
    for (int mt = 0; mt < 2; ++mt)
#pragma unroll
        for (int nt = 0; nt < 4; ++nt) {
            ah[mt][nt] = __builtin_amdgcn_mfma_f32_16x16x32_bf16(qa[mt][0], rb[nt][0], ah[mt][nt], 0, 0, 0);
            ah[mt][nt] = __builtin_amdgcn_mfma_f32_16x16x32_bf16(qa[mt][1], rb[nt][1], ah[mt][nt], 0, 0, 0);
            aw[mt][nt] = __builtin_amdgcn_mfma_f32_16x16x32_bf16(qa[mt][0], wb[nt][0], aw[mt][nt], 0, 0, 0);
            aw[mt][nt] = __builtin_amdgcn_mfma_f32_16x16x32_bf16(qa[mt][1], wb[nt][1], aw[mt][nt], 0, 0, 0);
        }
    __syncthreads();

    // ---- G_h ----
#pragma unroll
    for (int mt = 0; mt < 2; ++mt)
#pragma unroll
        for (int nt = 0; nt < 4; ++nt)
#pragma unroll
            for (int i = 0; i < 4; ++i)
                G[r0 + mt * 16 + quad * 4 + i][nt * 16 + col16] = ah[mt][nt][i];
    __syncthreads();
    for (int id = t; id < 2048; id += 256) {
        int tok = id >> 4, c2 = (id & 15) << 1;
        int i_img = (tc8 << 2) + (tok >> 5);
        float g0 = G[tok][i_img - c2 + 31];
        float g1 = G[tok][i_img - c2 + 30];
        unsigned pk = (unsigned)f2bf(g0) | ((unsigned)f2bf(g1) << 16);
        *(unsigned*)&qhb[(((size_t)bh << 10) + tok0 + tok) * 32 + c2] = pk;
    }
    __syncthreads();

    // ---- G_w ----
#pragma unroll
    for (int mt = 0; mt < 2; ++mt)
#pragma unroll
        for (int nt = 0; nt < 4; ++nt)
#pragma unroll
            for (int i = 0; i < 4; ++i)
                G[r0 + mt * 16 + quad * 4 + i][nt * 16 + col16] = aw[mt][nt][i];
    __syncthreads();
    for (int id = t; id < 2048; id += 256) {
        int tok = id >> 4, c2 = (id & 15) << 1;
        int j = tok & 31;
        float g0 = G[tok][j - c2 + 31];
        float g1 = G[tok][j - c2 + 30];
        unsigned pk = (unsigned)f2bf(g0) | ((unsigned)f2bf(g1) << 16);
        *(unsigned*)&qwb[(((size_t)bh << 10) + tok0 + tok) * 32 + c2] = pk;
    }
}

// ---------------------------------------------------------------------------
// R14: same as R13 (LDS-free, swapped QK^T, register K/V double-buffer), but
// __launch_bounds__(256, 2): VGPR cap 168 -> 256 so the prefetch buffers fit
// WITHOUT scratch spills (R13 evidence: WRITE_SIZE 12->37MB = spill stores;
// spill reload waitcnts drained the prefetch queue, keeping loads exposed).
// 2 blocks/CU; latency hidden by the now-materialized register pipeline.
// ---------------------------------------------------------------------------
__global__ __launch_bounds__(256, 2) void attn_mfma(
    const unsigned short* __restrict__ Q, const unsigned short* __restrict__ K,
    const unsigned short* __restrict__ Vt,
    const unsigned short* __restrict__ qhb, const unsigned short* __restrict__ qwb,
    unsigned short* __restrict__ Out)
{
    const int t   = threadIdx.x;
    const int id  = blockIdx.x;            // 0..3071
    const int xcd = id & 7;
    const int wq  = id >> 3;
    const int bh  = xcd * 12 + (wq % 12);
    const int qt  = wq / 12;               // 0..31
    const int b   = bh / 12;
    const int h   = bh - b * 12;
    const int q0  = qt << 5;

    __shared__ __align__(16) float qh_s[32][33];
    __shared__ __align__(16) float Obuf[4][32][68];
    __shared__ float red[4][32];

    const unsigned short* Kp = K  + (size_t)bh * 65536;
    const unsigned short* Vp = Vt + (size_t)bh * 65536;

    // stage qh (32 rows x 32 cols) bf16 -> f32, -16*log2e folded in
    {
        int row = t >> 3, c4 = (t & 7) << 2;
        const unsigned short* src = qhb + ((size_t)bh * 1024 + q0 + row) * 32 + c4;
        uint2 pk = *(const uint2*)src;
        qh_s[row][c4 + 0] = bf2f((unsigned short)(pk.x & 0xffff)) - EOFF;
        qh_s[row][c4 + 1] = bf2f((unsigned short)(pk.x >> 16))    - EOFF;
        qh_s[row][c4 + 2] = bf2f((unsigned short)(pk.y & 0xffff)) - EOFF;
        qh_s[row][c4 + 3] = bf2f((unsigned short)(pk.y >> 16))    - EOFF;
    }

    const int wv = t >> 6, lane = t & 63, c = lane & 15, qd = lane >> 4;

    // Q as B-frags (col = q-row, k = d)
    s8v qf[2][2];
    float uw[2][8];
#pragma unroll
    for (int mt = 0; mt < 2; ++mt) {
        const unsigned short* qp =
            Q + ((size_t)bh * 1024 + q0 + mt * 16 + c) * 64 + qd * 8;
        qf[mt][0] = *(const s8v*)qp;
        qf[mt][1] = *(const s8v*)(qp + 32);
        const unsigned short* wp =
            qwb + ((size_t)bh * 1024 + q0 + mt * 16 + c) * 32 + qd * 8;
        s8v w8 = *(const s8v*)wp;
#pragma unroll
        for (int j = 0; j < 8; ++j) uw[mt][j] = bf2f((unsigned short)w8[j]);
    }
    __syncthreads();

    const int perm0 = ((c >> 2) << 3) | (c & 3);   // A-row c -> kv 8*(c>>2)+(c&3)

    // kt-invariant lane base pointers; per-kt advance is a constant offset
    const unsigned short* kp0 = Kp + (size_t)((wv << 5) + perm0) * 64 + qd * 8;
    const unsigned short* vp0 = Vp + (size_t)c * 1024 + (wv << 5) + qd * 8;

    f4v o[2][4];
#pragma unroll
    for (int mt = 0; mt < 2; ++mt)
#pragma unroll
        for (int dt = 0; dt < 4; ++dt) {
            o[mt][dt][0] = 0.f; o[mt][dt][1] = 0.f;
            o[mt][dt][2] = 0.f; o[mt][dt][3] = 0.f;
        }
    float lp[2] = {0.f, 0.f};

    // prime the pipeline: kt=0 fragments
    s8v cka[4], cvb[4];
    cka[0] = *(const s8v*)(kp0);            // T0, d 0..31
    cka[1] = *(const s8v*)(kp0 + 32);       // T0, d 32..63
    cka[2] = *(const s8v*)(kp0 + 256);      // T1 (+4 rows)
    cka[3] = *(const s8v*)(kp0 + 288);
    cvb[0] = *(const s8v*)(vp0);
    cvb[1] = *(const s8v*)(vp0 + 16384);
    cvb[2] = *(const s8v*)(vp0 + 32768);
    cvb[3] = *(const s8v*)(vp0 + 49152);

#pragma unroll
    for (int kt = 0; kt < 8; ++kt) {
        // ---- prefetch kt+1 into next-regs (issued before any use of cur) ----
        s8v nka[4], nvb[4];
        if (kt < 7) {
            const unsigned short* kpn = kp0 + (kt + 1) * 8192;  // +128 kv rows
            const unsigned short* vpn = vp0 + (kt + 1) * 128;   // +128 toks
            nka[0] = *(const s8v*)(kpn);
            nka[1] = *(const s8v*)(kpn + 32);
            nka[2] = *(const s8v*)(kpn + 256);
            nka[3] = *(const s8v*)(kpn + 288);
            nvb[0] = *(const s8v*)(vpn);
            nvb[1] = *(const s8v*)(vpn + 16384);
            nvb[2] = *(const s8v*)(vpn + 32768);
            nvb[3] = *(const s8v*)(vpn + 49152);
        }

        float qhv0 = qh_s[c][(kt << 2) + wv];
        float qhv1 = qh_s[16 + c][(kt << 2) + wv];

        s8v pa[2];
#pragma unroll
        for (int mt = 0; mt < 2; ++mt) {
            const float qhv = mt ? qhv1 : qhv0;
            f4v c0, c1;
            c0[0] = 0.f; c0[1] = 0.f; c0[2] = 0.f; c0[3] = 0.f;
            c1[0] = 0.f; c1[1] = 0.f; c1[2] = 0.f; c1[3] = 0.f;
            c0 = __builtin_amdgcn_mfma_f32_16x16x32_bf16(cka[0], qf[mt][0], c0, 0, 0, 0);
            c0 = __builtin_amdgcn_mfma_f32_16x16x32_bf16(cka[1], qf[mt][1], c0, 0, 0, 0);
            c1 = __builtin_amdgcn_mfma_f32_16x16x32_bf16(cka[2], qf[mt][0], c1, 0, 0, 0);
            c1 = __builtin_amdgcn_mfma_f32_16x16x32_bf16(cka[3], qf[mt][1], c1, 0, 0, 0);
            s8v p;
#pragma unroll
            for (int j = 0; j < 4; ++j) {
                float pe = __builtin_amdgcn_exp2f(c0[j] + qhv + uw[mt][j]);
                lp[mt] += pe;
                p[j] = (short)f2bf(pe);
            }
#pragma unroll
            for (int j = 0; j < 4; ++j) {
                float pe = __builtin_amdgcn_exp2f(c1[j] + qhv + uw[mt][4 + j]);
                lp[mt] += pe;
                p[4 + j] = (short)f2bf(pe);
            }
            pa[mt] = p;
        }
#pragma unroll
        for (int mt = 0; mt < 2; ++mt)
#pragma unroll
            for (int dt = 0; dt < 4; ++dt)
                o[mt][dt] = __builtin_amdgcn_mfma_f32_16x16x32_bf16(
                    pa[mt], cvb[dt], o[mt][dt], 0, 0, 0);

        // ---- rotate buffers (renamed away under full unroll) ----
        if (kt < 7) {
#pragma unroll
            for (int r = 0; r < 4; ++r) { cka[r] = nka[r]; cvb[r] = nvb[r]; }
        }
    }

    // ---- reductions ----
#pragma unroll
    for (int mt = 0; mt < 2; ++mt) {
        lp[mt] += __shfl_xor(lp[mt], 16);
        lp[mt] += __shfl_xor(lp[mt], 32);
    }
    if (qd == 0) { red[wv][c] = lp[0]; red[wv][16 + c] = lp[1]; }
#pragma unroll
    for (int mt = 0; mt < 2; ++mt)
#pragma unroll
        for (int dt = 0; dt < 4; ++dt)
#pragma unroll
            for (int r = 0; r < 4; ++r)
                Obuf[wv][mt * 16 + qd * 4 + r][dt * 16 + c] = o[mt][dt][r];
    __syncthreads();

    {
        const int q = t >> 3, d8 = (t & 7) << 3;
        float inv = 1.f / (red[0][q] + red[1][q] + red[2][q] + red[3][q]);
        f4v s0 = *(const f4v*)&Obuf[0][q][d8];
        f4v s1 = *(const f4v*)&Obuf[0][q][d8 + 4];
#pragma unroll
        for (int w = 1; w < 4; ++w) {
            s0 += *(const f4v*)&Obuf[w][q][d8];
            s1 += *(const f4v*)&Obuf[w][q][d8 + 4];
        }
        uint4 pk;
        pk.x = (unsigned)f2bf(s0[0] * inv) | ((unsigned)f2bf(s0[1] * inv) << 16);
        pk.y = (unsigned)f2bf(s0[2] * inv) | ((unsigned)f2bf(s0[3] * inv) << 16);
        pk.z = (unsigned)f2bf(s1[0] * inv) | ((unsigned)f2bf(s1[1] * inv) << 16);
        pk.w = (unsigned)f2bf(s1[2] * inv) | ((unsigned)f2bf(s1[3] * inv) << 16);
        *(uint4*)(Out + ((size_t)b * 1024 + q0 + q) * 768 + h * 64 + d8) = pk;
    }
}

extern "C" void kernel_launch(void* const* d_in, const int* in_sizes, int n_in,
                              void* d_out, int out_size, void* d_ws, size_t ws_size,
                              hipStream_t stream) {
    const float* x      = (const float*)d_in[0];
    const float* qkv_w  = (const float*)d_in[1];
    const float* qkv_b  = (const float*)d_in[2];
    const float* proj_w = (const float*)d_in[3];
    const float* proj_b = (const float*)d_in[4];
    const float* rel_h  = (const float*)d_in[5];
    const float* rel_w  = (const float*)d_in[6];
    float* out = (float*)d_out;

    char* ws = (char*)d_ws;
    unsigned short* qbuf  = (unsigned short*)(ws);             // bf16 [96][1024][64] 12582912
    unsigned short* kbuf  = (unsigned short*)(ws + 12582912);  // bf16 [96][1024][64] 12582912
    unsigned short* vtbuf = (unsigned short*)(ws + 25165824);  // bf16 [96][64][1024] 12582912
    unsigned short* xab   = (unsigned short*)(ws + 37748736);  // bf16 x / attn-out   12582912
    unsigned short* wqb   = (unsigned short*)(ws + 50331648);  // bf16 qkv_w          3538944
    unsigned short* wpb   = (unsigned short*)(ws + 53870592);  // bf16 proj_w         1179648
    unsigned short* qhb   = (unsigned short*)(ws + 55050240);  // bf16 [96][1024][32] 6291456
    unsigned short* qwb   = (unsigned short*)(ws + 61341696);  // bf16 [96][1024][32] 6291456

    to_bf16_all<<<4224, 256, 0, stream>>>(x, qkv_w, proj_w, xab, wqb, wpb);
    qkv_gemm_mfma<<<dim3(18, 64), 256, 0, stream>>>(xab, wqb, qkv_b, qbuf, kbuf, vtbuf);
    bias_prep_mfma<<<dim3(8, 96), 256, 0, stream>>>(qbuf, rel_h, rel_w, qhb, qwb);
    attn_mfma<<<3072, 256, 0, stream>>>(qbuf, kbuf, vtbuf, qhb, qwb, xab);
    proj_gemm_mfma<<<dim3(6, 64), 256, 0, stream>>>(xab, wpb, proj_b, out);
}

// Round 6
// 226.135 us; speedup vs baseline: 1.2418x; 1.2418x over previous
//
#include <hip/hip_runtime.h>
#include <cstddef>

typedef short s4v __attribute__((ext_vector_type(4)));
typedef short s8v __attribute__((ext_vector_type(8)));
typedef float f4v __attribute__((ext_vector_type(4)));

__device__ __forceinline__ unsigned short f2bf(float f) {
    union { float f; unsigned u; } v; v.f = f;
    unsigned r = v.u + 0x7fff + ((v.u >> 16) & 1);
    return (unsigned short)(r >> 16);
}
__device__ __forceinline__ float bf2f(unsigned short u) {
    union { unsigned u; float f; } v; v.u = ((unsigned)u) << 16;
    return v.f;
}

// async global->LDS, 16B per lane. LDS dest is wave-uniform base + lane*16.
__device__ __forceinline__ void gl_lds16(const void* g, void* l) {
    __builtin_amdgcn_global_load_lds(
        (const __attribute__((address_space(1))) void*)g,
        (__attribute__((address_space(3))) void*)l, 16, 0, 0);
}

#define QSC   0.18033688011112043f   /* 0.125 * log2(e) */
#define EOFF  23.082320654223414f    /* 16 * log2(e) */

// ---------------------------------------------------------------------------
// Fused f32 -> bf16 conversion for x, qkv_w, proj_w (one launch).
// ---------------------------------------------------------------------------
__global__ __launch_bounds__(256) void to_bf16_all(
    const float* __restrict__ x, const float* __restrict__ qw,
    const float* __restrict__ pw, unsigned short* __restrict__ xd,
    unsigned short* __restrict__ qd, unsigned short* __restrict__ pd)
{
    int i = blockIdx.x * 256 + threadIdx.x;
    const float* s; unsigned short* d; int j;
    if (i < 786432)       { s = x;  d = xd; j = i; }
    else if (i < 1007616) { s = qw; d = qd; j = i - 786432; }
    else                  { s = pw; d = pd; j = i - 1007616; }
    float4 f0 = ((const float4*)s)[j * 2];
    float4 f1 = ((const float4*)s)[j * 2 + 1];
    uint4 pk;
    pk.x = (unsigned)f2bf(f0.x) | ((unsigned)f2bf(f0.y) << 16);
    pk.y = (unsigned)f2bf(f0.z) | ((unsigned)f2bf(f0.w) << 16);
    pk.z = (unsigned)f2bf(f1.x) | ((unsigned)f2bf(f1.y) << 16);
    pk.w = (unsigned)f2bf(f1.z) | ((unsigned)f2bf(f1.w) << 16);
    ((uint4*)d)[j] = pk;
}

// ---------------------------------------------------------------------------
// bf16 MFMA GEMM, m97 structure: 128x128 tile, BK=32, 256 thr = 4 waves.
// ---------------------------------------------------------------------------
__global__ __launch_bounds__(256) void qkv_gemm_mfma(
    const unsigned short* __restrict__ A, const unsigned short* __restrict__ W,
    const float* __restrict__ bias,
    unsigned short* __restrict__ qb, unsigned short* __restrict__ kb,
    unsigned short* __restrict__ vt)
{
    __shared__ __align__(16) unsigned short As[128 * 32];
    __shared__ __align__(16) unsigned short Bs[128 * 32];
    const int t     = threadIdx.x;
    const int bc    = blockIdx.x;   // N = 2304 -> 18
    const int br    = blockIdx.y;   // M = 8192 -> 64
    const int wv    = t >> 6;
    const int lane  = t & 63;
    const int col16 = lane & 15;
    const int quad  = lane >> 4;
    const int w4    = lane >> 2;
    const int k8    = (lane & 3) << 3;
    const int mw    = wv >> 1, nw = wv & 1;

    const unsigned short* Ag = A + (size_t)(br * 128 + (wv << 5) + w4) * 768 + k8;
    const unsigned short* Wg = W + (size_t)(bc * 128 + (wv << 5) + w4) * 768 + k8;
    unsigned short* Asw = &As[(wv << 5) * 32];
    unsigned short* Bsw = &Bs[(wv << 5) * 32];

    f4v acc[4][4];
#pragma unroll
    for (int mt = 0; mt < 4; ++mt)
#pragma unroll
        for (int nt = 0; nt < 4; ++nt) {
            acc[mt][nt][0] = 0.f; acc[mt][nt][1] = 0.f;
            acc[mt][nt][2] = 0.f; acc[mt][nt][3] = 0.f;
        }

    for (int k0 = 0; k0 < 768; k0 += 32) {
        __syncthreads();
        gl_lds16(Ag + k0,             Asw);
        gl_lds16(Ag + k0 + 16 * 768,  Asw + 16 * 32);
        gl_lds16(Wg + k0,             Bsw);
        gl_lds16(Wg + k0 + 16 * 768,  Bsw + 16 * 32);
        __syncthreads();

        s8v a[4], b[4];
#pragma unroll
        for (int mt = 0; mt < 4; ++mt)
            a[mt] = *(const s8v*)&As[(mw * 64 + mt * 16 + col16) * 32 + quad * 8];
#pragma unroll
        for (int nt = 0; nt < 4; ++nt)
            b[nt] = *(const s8v*)&Bs[(nw * 64 + nt * 16 + col16) * 32 + quad * 8];
#pragma unroll
        for (int mt = 0; mt < 4; ++mt)
#pragma unroll
            for (int nt = 0; nt < 4; ++nt)
                acc[mt][nt] = __builtin_amdgcn_mfma_f32_16x16x32_bf16(
                    a[mt], b[nt], acc[mt][nt], 0, 0, 0);
    }

    const int which = bc / 6;
    const int cb    = (bc % 6) * 128 + nw * 64;
    const int m0    = br * 128 + mw * 64 + quad * 4;
    if (which == 2) {
        // V transposed: [bh][d][tok], 4 consecutive toks per b64 store
#pragma unroll
        for (int nt = 0; nt < 4; ++nt) {
            int c    = cb + nt * 16 + col16;
            int head = c >> 6, d = c & 63;
            float bv = bias[1536 + c];
#pragma unroll
            for (int mt = 0; mt < 4; ++mt) {
                int mb  = m0 + mt * 16;
                int bbk = mb >> 10, tok = mb & 1023;
                uint2 pk;
                pk.x = (unsigned)f2bf(acc[mt][nt][0] + bv)
                     | ((unsigned)f2bf(acc[mt][nt][1] + bv) << 16);
                pk.y = (unsigned)f2bf(acc[mt][nt][2] + bv)
                     | ((unsigned)f2bf(acc[mt][nt][3] + bv) << 16);
                *(uint2*)&vt[((size_t)(bbk * 12 + head)) * 65536 + (size_t)d * 1024 + tok] = pk;
            }
        }
    } else {
        // q carries 0.125*log2e so downstream softmax can use exp2 directly
        const float sc = (which == 0) ? QSC : 1.0f;
        unsigned short* dst = (which == 0) ? qb : kb;
#pragma unroll
        for (int nt = 0; nt < 4; ++nt) {
            int c    = cb + nt * 16 + col16;
            int head = c >> 6, d = c & 63;
            float bv = bias[which * 768 + c];
#pragma unroll
            for (int mt = 0; mt < 4; ++mt) {
#pragma unroll
                for (int i = 0; i < 4; ++i) {
                    int m   = m0 + mt * 16 + i;
                    int bbk = m >> 10, tok = m & 1023;
                    dst[(((size_t)(bbk * 12 + head) << 10) + tok) * 64 + d] =
                        f2bf((acc[mt][nt][i] + bv) * sc);
                }
            }
        }
    }
}

__global__ __launch_bounds__(256) void proj_gemm_mfma(
    const unsigned short* __restrict__ A, const unsigned short* __restrict__ W,
    const float* __restrict__ bias, float* __restrict__ Out)
{
    __shared__ __align__(16) unsigned short As[128 * 32];
    __shared__ __align__(16) unsigned short Bs[128 * 32];
    const int t     = threadIdx.x;
    const int bc    = blockIdx.x;
    const int br    = blockIdx.y;
    const int wv    = t >> 6;
    const int lane  = t & 63;
    const int col16 = lane & 15;
    const int quad  = lane >> 4;
    const int w4    = lane >> 2;
    const int k8    = (lane & 3) << 3;
    const int mw    = wv >> 1, nw = wv & 1;

    const unsigned short* Ag = A + (size_t)(br * 128 + (wv << 5) + w4) * 768 + k8;
    const unsigned short* Wg = W + (size_t)(bc * 128 + (wv << 5) + w4) * 768 + k8;
    unsigned short* Asw = &As[(wv << 5) * 32];
    unsigned short* Bsw = &Bs[(wv << 5) * 32];

    f4v acc[4][4];
#pragma unroll
    for (int mt = 0; mt < 4; ++mt)
#pragma unroll
        for (int nt = 0; nt < 4; ++nt) {
            acc[mt][nt][0] = 0.f; acc[mt][nt][1] = 0.f;
            acc[mt][nt][2] = 0.f; acc[mt][nt][3] = 0.f;
        }

    for (int k0 = 0; k0 < 768; k0 += 32) {
        __syncthreads();
        gl_lds16(Ag + k0,             Asw);
        gl_lds16(Ag + k0 + 16 * 768,  Asw + 16 * 32);
        gl_lds16(Wg + k0,             Bsw);
        gl_lds16(Wg + k0 + 16 * 768,  Bsw + 16 * 32);
        __syncthreads();

        s8v a[4], b[4];
#pragma unroll
        for (int mt = 0; mt < 4; ++mt)
            a[mt] = *(const s8v*)&As[(mw * 64 + mt * 16 + col16) * 32 + quad * 8];
#pragma unroll
        for (int nt = 0; nt < 4; ++nt)
            b[nt] = *(const s8v*)&Bs[(nw * 64 + nt * 16 + col16) * 32 + quad * 8];
#pragma unroll
        for (int mt = 0; mt < 4; ++mt)
#pragma unroll
            for (int nt = 0; nt < 4; ++nt)
                acc[mt][nt] = __builtin_amdgcn_mfma_f32_16x16x32_bf16(
                    a[mt], b[nt], acc[mt][nt], 0, 0, 0);
    }

    const int m0 = br * 128 + mw * 64 + quad * 4;
#pragma unroll
    for (int nt = 0; nt < 4; ++nt) {
        int c    = bc * 128 + nw * 64 + nt * 16 + col16;
        float bv = bias[c];
#pragma unroll
        for (int mt = 0; mt < 4; ++mt) {
#pragma unroll
            for (int i = 0; i < 4; ++i) {
                int m = m0 + mt * 16 + i;
                Out[(size_t)m * 768 + c] = acc[mt][nt][i] + bv;
            }
        }
    }
}

// ---------------------------------------------------------------------------
// Bias-table precompute via MFMA.
// ---------------------------------------------------------------------------
__global__ __launch_bounds__(256) void bias_prep_mfma(
    const unsigned short* __restrict__ Q, const float* __restrict__ Rh,
    const float* __restrict__ Rw, unsigned short* __restrict__ qhb,
    unsigned short* __restrict__ qwb)
{
    __shared__ __align__(16) char smem[36864];
    unsigned short (*Qs)[72]  = (unsigned short (*)[72])smem;
    unsigned short (*Rs)[72]  = (unsigned short (*)[72])(smem + 18432);
    unsigned short (*Wsm)[72] = (unsigned short (*)[72])(smem + 27648);
    float (*G)[66]            = (float (*)[66])smem;

    const int t    = threadIdx.x;
    const int tc8  = blockIdx.x;   // 0..7 : 128-token chunk
    const int bh   = blockIdx.y;   // 0..95
    const int tok0 = tc8 << 7;

    for (int id = t; id < 1024; id += 256) {
        int row = id >> 3, g8 = (id & 7) << 3;
        *(uint4*)&Qs[row][g8] =
            *(const uint4*)(Q + ((size_t)bh * 1024 + tok0 + row) * 64 + g8);
    }
    for (int id = t; id < 512; id += 256) {
        int row = id >> 3, g8 = (id & 7) << 3;
        unsigned short* dh = &Rs[row][g8];
        unsigned short* dw = &Wsm[row][g8];
        if (row < 63) {
            const float* sh = Rh + row * 64 + g8;
            const float* sw = Rw + row * 64 + g8;
            float4 a = *(const float4*)sh; float4 b = *(const float4*)(sh + 4);
            float4 c = *(const float4*)sw; float4 d = *(const float4*)(sw + 4);
            dh[0] = f2bf(a.x); dh[1] = f2bf(a.y); dh[2] = f2bf(a.z); dh[3] = f2bf(a.w);
            dh[4] = f2bf(b.x); dh[5] = f2bf(b.y); dh[6] = f2bf(b.z); dh[7] = f2bf(b.w);
            dw[0] = f2bf(c.x); dw[1] = f2bf(c.y); dw[2] = f2bf(c.z); dw[3] = f2bf(c.w);
            dw[4] = f2bf(d.x); dw[5] = f2bf(d.y); dw[6] = f2bf(d.z); dw[7] = f2bf(d.w);
        } else {
#pragma unroll
            for (int j = 0; j < 8; ++j) { dh[j] = 0; dw[j] = 0; }
        }
    }
    __syncthreads();

    const int wv    = t >> 6;
    const int lane  = t & 63;
    const int col16 = lane & 15;
    const int quad  = lane >> 4;
    const int r0    = wv << 5;

    s8v qa[2][2], rb[4][2], wb[4][2];
#pragma unroll
    for (int mt = 0; mt < 2; ++mt)
#pragma unroll
        for (int kc = 0; kc < 2; ++kc)
            qa[mt][kc] = *(const s8v*)&Qs[r0 + mt * 16 + col16][kc * 32 + quad * 8];
#pragma unroll
    for (int nt = 0; nt < 4; ++nt)
#pragma unroll
        for (int kc = 0; kc < 2; ++kc) {
            rb[nt][kc] = *(const s8v*)&Rs[nt * 16 + col16][kc * 32 + quad * 8];
            wb[nt][kc] = *(const s8v*)&Wsm[nt * 16 + col16][kc * 32 + quad * 8];
        }

    f4v ah[2][4], aw[2][4];
#pragma unroll
    for (int mt = 0; mt < 2; ++mt)
#pragma unroll
        for (int nt = 0; nt < 4; ++nt) {
            f4v z; z[0] = 0.f; z[1] = 0.f; z[2] = 0.f; z[3] = 0.f;
            ah[mt][nt] = z; aw[mt][nt] = z;
        }
#pragma unroll
    for (int mt = 0; mt < 2; ++mt)
#pragma unroll
        for (int nt = 0; nt < 4; ++nt) {
            ah[mt][nt] = __builtin_amdgcn_mfma_f32_16x16x32_bf16(qa[mt][0], rb[nt][0], ah[mt][nt], 0, 0, 0);
            ah[mt][nt] = __builtin_amdgcn_mfma_f32_16x16x32_bf16(qa[mt][1], rb[nt][1], ah[mt][nt], 0, 0, 0);
            aw[mt][nt] = __builtin_amdgcn_mfma_f32_16x16x32_bf16(qa[mt][0], wb[nt][0], aw[mt][nt], 0, 0, 0);
            aw[mt][nt] = __builtin_amdgcn_mfma_f32_16x16x32_bf16(qa[mt][1], wb[nt][1], aw[mt][nt], 0, 0, 0);
        }
    __syncthreads();

    // ---- G_h ----
#pragma unroll
    for (int mt = 0; mt < 2; ++mt)
#pragma unroll
        for (int nt = 0; nt < 4; ++nt)
#pragma unroll
            for (int i = 0; i < 4; ++i)
                G[r0 + mt * 16 + quad * 4 + i][nt * 16 + col16] = ah[mt][nt][i];
    __syncthreads();
    for (int id = t; id < 2048; id += 256) {
        int tok = id >> 4, c2 = (id & 15) << 1;
        int i_img = (tc8 << 2) + (tok >> 5);
        float g0 = G[tok][i_img - c2 + 31];
        float g1 = G[tok][i_img - c2 + 30];
        unsigned pk = (unsigned)f2bf(g0) | ((unsigned)f2bf(g1) << 16);
        *(unsigned*)&qhb[(((size_t)bh << 10) + tok0 + tok) * 32 + c2] = pk;
    }
    __syncthreads();

    // ---- G_w ----
#pragma unroll
    for (int mt = 0; mt < 2; ++mt)
#pragma unroll
        for (int nt = 0; nt < 4; ++nt)
#pragma unroll
            for (int i = 0; i < 4; ++i)
                G[r0 + mt * 16 + quad * 4 + i][nt * 16 + col16] = aw[mt][nt][i];
    __syncthreads();
    for (int id = t; id < 2048; id += 256) {
        int tok = id >> 4, c2 = (id & 15) << 1;
        int j = tok & 31;
        float g0 = G[tok][j - c2 + 31];
        float g1 = G[tok][j - c2 + 30];
        unsigned pk = (unsigned)f2bf(g0) | ((unsigned)f2bf(g1) << 16);
        *(unsigned*)&qwb[(((size_t)bh << 10) + tok0 + tok) * 32 + c2] = pk;
    }
}

// ---------------------------------------------------------------------------
// R15: R9 block structure (64q x 64kv tiles, LDS-staged K/V double-buffered,
// 4 blocks/CU) + swapped QK^T so P NEVER touches LDS (R12's verified
// fragment identity). K is stored into LDS PRE-PERMUTED: LDS row
// L(g) = (g&32)|((g&4)<<2)|((g&24)>>1)|(g&3) holds K token g, so QK^T A-frag
// reads are 16 CONSECUTIVE rows (R9's proven conflict pattern) while the
// output fragment lands exactly in the PV A-frag layout:
//   A-tile T at rows T*16+c  ->  lane scores kv = T<2 ? 8*qd+(T&1)*4+i
//                                              : 32+8*qd+(T&1)*4+i
//   -> pa0 = P[q=c][kv=8qd+j], pa1 = P[q=c][kv=32+8qd+j]  (PV A-frags).
// Eliminated per wave/kt vs R9: 64 ds_write_b16 + 4 ds_read_b64 (P round
// trip) + lgkmcnt wait + its bank conflicts. MFMA count unchanged (16).
// ---------------------------------------------------------------------------
__global__ __launch_bounds__(256, 4) void attn_mfma(
    const unsigned short* __restrict__ Q, const unsigned short* __restrict__ K,
    const unsigned short* __restrict__ Vt,
    const unsigned short* __restrict__ qhb, const unsigned short* __restrict__ qwb,
    unsigned short* __restrict__ Out)
{
    const int t  = threadIdx.x;
    const int id  = blockIdx.x;           // 0..1535
    const int xcd = id & 7;
    const int wq  = id >> 3;
    const int bh  = xcd * 12 + (wq % 12);
    const int qt2 = wq / 12;
    const int b   = bh / 12;
    const int h   = bh - b * 12;
    const int q0  = qt2 << 6;

    __shared__ __align__(16) unsigned short Ks[64 * 72];
    __shared__ __align__(16) unsigned short Vs[64 * 72];
    __shared__ float qh_s[64][33];

    const unsigned short* Kp = K  + (size_t)bh * 65536;
    const unsigned short* Vp = Vt + (size_t)bh * 65536;

    // stage qh (64 rows x 32 cols) bf16 -> f32, -16*log2e folded in
    {
        const unsigned* qhp = (const unsigned*)(qhb + ((size_t)bh * 1024 + q0) * 32);
        for (int i2 = t; i2 < 1024; i2 += 256) {
            int row = i2 >> 4, c2 = (i2 & 15) << 1;
            unsigned ph = qhp[i2];
            qh_s[row][c2]     = bf2f((unsigned short)(ph & 0xffff)) - EOFF;
            qh_s[row][c2 + 1] = bf2f((unsigned short)(ph >> 16))    - EOFF;
        }
    }

    const int wv = t >> 6;
    const int lane = t & 63;
    const int c  = lane & 15;     // q-column within wave's 16 rows
    const int qd = lane >> 4;     // quad

    // Q as B-frags (col = q-row = c, k = d); rel_w bias into 8 regs (kv&31 =
    // 8*qd+j is kt-invariant per lane).
    s8v qf0, qf1;
    float uw[8];
    {
        const size_t row = (size_t)bh * 1024 + q0 + (wv << 4) + c;
        const unsigned short* qp = Q + row * 64 + qd * 8;
        qf0 = *(const s8v*)qp;
        qf1 = *(const s8v*)(qp + 32);
        s8v w8 = *(const s8v*)(qwb + row * 32 + qd * 8);
#pragma unroll
        for (int j = 0; j < 8; ++j) uw[j] = bf2f((unsigned short)w8[j]);
    }

    // initial K/V tile: K stored permuted (row L(g)), V as-is (rows = d)
    const int e0 = t * 8, e1 = t * 8 + 2048;
    const int g0 = e0 >> 6, g1 = e1 >> 6, s0 = e0 & 63, s1 = e1 & 63;
    const int L0 = (g0 & 32) | ((g0 & 4) << 2) | ((g0 & 24) >> 1) | (g0 & 3);
    const int L1 = (g1 & 32) | ((g1 & 4) << 2) | ((g1 & 24) >> 1) | (g1 & 3);
    {
        uint4 pk0 = *(const uint4*)(Kp + e0);
        uint4 pk1 = *(const uint4*)(Kp + e1);
        uint4 pv0 = *(const uint4*)(Vp + (size_t)g0 * 1024 + s0);
        uint4 pv1 = *(const uint4*)(Vp + (size_t)g1 * 1024 + s1);
        *(uint4*)&Ks[L0 * 72 + s0] = pk0;
        *(uint4*)&Ks[L1 * 72 + s1] = pk1;
        *(uint4*)&Vs[g0 * 72 + s0] = pv0;
        *(uint4*)&Vs[g1 * 72 + s1] = pv1;
    }
    __syncthreads();

    f4v o[4];
#pragma unroll
    for (int dt = 0; dt < 4; ++dt) { o[dt][0] = 0.f; o[dt][1] = 0.f; o[dt][2] = 0.f; o[dt][3] = 0.f; }
    float lp = 0.f;

    for (int kt = 0; kt < 16; ++kt) {
        uint4 pk0, pk1, pv0, pv1;
        if (kt < 15) {
            const int k0n = (kt + 1) << 6;
            pk0 = *(const uint4*)(Kp + (size_t)k0n * 64 + e0);
            pk1 = *(const uint4*)(Kp + (size_t)k0n * 64 + e1);
            pv0 = *(const uint4*)(Vp + (size_t)g0 * 1024 + k0n + s0);
            pv1 = *(const uint4*)(Vp + (size_t)g1 * 1024 + k0n + s1);
        }

        // ---- QK^T swapped: A = permuted K rows (consecutive), B = Q ----
        f4v sc[4];
#pragma unroll
        for (int T = 0; T < 4; ++T) {
            s8v lo = *(const s8v*)&Ks[(T * 16 + c) * 72 + qd * 8];
            s8v hi = *(const s8v*)&Ks[(T * 16 + c) * 72 + 32 + qd * 8];
            f4v z; z[0] = 0.f; z[1] = 0.f; z[2] = 0.f; z[3] = 0.f;
            z = __builtin_amdgcn_mfma_f32_16x16x32_bf16(lo, qf0, z, 0, 0, 0);
            z = __builtin_amdgcn_mfma_f32_16x16x32_bf16(hi, qf1, z, 0, 0, 0);
            sc[T] = z;
        }

        const float qhv0 = qh_s[(wv << 4) + c][(kt << 1)];
        const float qhv1 = qh_s[(wv << 4) + c][(kt << 1) + 1];

        // ---- softmax in registers; pa frags are PV A-operands directly ----
        s8v pa0, pa1;
#pragma unroll
        for (int j = 0; j < 4; ++j) {
            float pe = __builtin_amdgcn_exp2f(sc[0][j] + qhv0 + uw[j]);
            lp += pe; pa0[j] = (short)f2bf(pe);
        }
#pragma unroll
        for (int j = 0; j < 4; ++j) {
            float pe = __builtin_amdgcn_exp2f(sc[1][j] + qhv0 + uw[4 + j]);
            lp += pe; pa0[4 + j] = (short)f2bf(pe);
        }
#pragma unroll
        for (int j = 0; j < 4; ++j) {
            float pe = __builtin_amdgcn_exp2f(sc[2][j] + qhv1 + uw[j]);
            lp += pe; pa1[j] = (short)f2bf(pe);
        }
#pragma unroll
        for (int j = 0; j < 4; ++j) {
            float pe = __builtin_amdgcn_exp2f(sc[3][j] + qhv1 + uw[4 + j]);
            lp += pe; pa1[4 + j] = (short)f2bf(pe);
        }

        // ---- PV ----
#pragma unroll
        for (int dt = 0; dt < 4; ++dt) {
            s8v vlo = *(const s8v*)&Vs[(dt * 16 + c) * 72 + qd * 8];
            s8v vhi = *(const s8v*)&Vs[(dt * 16 + c) * 72 + 32 + qd * 8];
            o[dt] = __builtin_amdgcn_mfma_f32_16x16x32_bf16(pa0, vlo, o[dt], 0, 0, 0);
            o[dt] = __builtin_amdgcn_mfma_f32_16x16x32_bf16(pa1, vhi, o[dt], 0, 0, 0);
        }

        __syncthreads();
        if (kt < 15) {
            *(uint4*)&Ks[L0 * 72 + s0] = pk0;
            *(uint4*)&Ks[L1 * 72 + s1] = pk1;
            *(uint4*)&Vs[g0 * 72 + s0] = pv0;
            *(uint4*)&Vs[g1 * 72 + s1] = pv1;
        }
        __syncthreads();
    }

    // lane holds lp for q=c over its quad's kv subset; reduce across quads
    lp += __shfl_xor(lp, 16);
    lp += __shfl_xor(lp, 32);

#pragma unroll
    for (int i = 0; i < 4; ++i) {
        float inv = 1.f / __shfl(lp, (qd << 2) + i);
        int qr = q0 + (wv << 4) + (qd << 2) + i;
        unsigned short* dst = Out + ((size_t)b * 1024 + qr) * 768 + h * 64;
#pragma unroll
        for (int dt = 0; dt < 4; ++dt)
            dst[dt * 16 + c] = f2bf(o[dt][i] * inv);
    }
}

extern "C" void kernel_launch(void* const* d_in, const int* in_sizes, int n_in,
                              void* d_out, int out_size, void* d_ws, size_t ws_size,
                              hipStream_t stream) {
    const float* x      = (const float*)d_in[0];
    const float* qkv_w  = (const float*)d_in[1];
    const float* qkv_b  = (const float*)d_in[2];
    const float* proj_w = (const float*)d_in[3];
    const float* proj_b = (const float*)d_in[4];
    const float* rel_h  = (const float*)d_in[5];
    const float* rel_w  = (const float*)d_in[6];
    float* out = (float*)d_out;

    char* ws = (char*)d_ws;
    unsigned short* qbuf  = (unsigned short*)(ws);             // bf16 [96][1024][64] 12582912
    unsigned short* kbuf  = (unsigned short*)(ws + 12582912);  // bf16 [96][1024][64] 12582912
    unsigned short* vtbuf = (unsigned short*)(ws + 25165824);  // bf16 [96][64][1024] 12582912
    unsigned short* xab   = (unsigned short*)(ws + 37748736);  // bf16 x / attn-out   12582912
    unsigned short* wqb   = (unsigned short*)(ws + 50331648);  // bf16 qkv_w          3538944
    unsigned short* wpb   = (unsigned short*)(ws + 53870592);  // bf16 proj_w         1179648
    unsigned short* qhb   = (unsigned short*)(ws + 55050240);  // bf16 [96][1024][32] 6291456
    unsigned short* qwb   = (unsigned short*)(ws + 61341696);  // bf16 [96][1024][32] 6291456

    to_bf16_all<<<4224, 256, 0, stream>>>(x, qkv_w, proj_w, xab, wqb, wpb);
    qkv_gemm_mfma<<<dim3(18, 64), 256, 0, stream>>>(xab, wqb, qkv_b, qbuf, kbuf, vtbuf);
    bias_prep_mfma<<<dim3(8, 96), 256, 0, stream>>>(qbuf, rel_h, rel_w, qhb, qwb);
    attn_mfma<<<1536, 256, 0, stream>>>(qbuf, kbuf, vtbuf, qhb, qwb, xab);
    proj_gemm_mfma<<<dim3(6, 64), 256, 0, stream>>>(xab, wpb, proj_b, out);
}